// Round 4
// baseline (136.701 us; speedup 1.0000x reference)
//
#include <hip/hip_runtime.h>
#include <math.h>

// SSIM on MI355X, round 4: vertical-first separable conv, 64x16 tiles,
// 320 threads (280 column tasks map 1:1 -> no serialized extra task),
// 23 KB LDS -> ~6 blocks/CU occupancy, single-pass horizontal phase.

#define WI 320
#define HI 320
#define NI 64
#define TW 64
#define TH 16
#define GXD 5                  // WI/TW
#define GYD 20                 // HI/TH
#define NBLK (GXD * GYD * NI)  // 6400
#define LSTR 72                // vfilt row stride in floats (288 B, 16B-aligned)
#define NPIX ((double)NI * WI * HI)

typedef float v4 __attribute__((ext_vector_type(4)));

struct W7 { float w[7]; };

// Vertical 7-tap for one column task: band (4 output rows), vfilt column ci
// (0..69; image col = tx0+ci-3). Streams 10 input rows, accumulates
// 5 channels x 4 rows in registers, writes vfilt[ch][band*4+r][ci].
template <bool INTERIOR>
__device__ __forceinline__ void column_task(
    const float* __restrict__ Xn, const float* __restrict__ Yn,
    const W7& wv, float* __restrict__ vbuf, int tx0, int ty0, int band, int ci)
{
    const int gx  = tx0 + ci - 3;
    const bool xok = (unsigned)gx < (unsigned)WI;
    const int gy0 = ty0 + band * 4 - 3;

    float acc[5][4];
#pragma unroll
    for (int ch = 0; ch < 5; ++ch)
#pragma unroll
        for (int r = 0; r < 4; ++r) acc[ch][r] = 0.f;

#pragma unroll
    for (int j = 0; j < 10; ++j) {
        const int gy = gy0 + j;
        float xv = 0.f, yv = 0.f;
        const bool ok = INTERIOR ? xok : (xok && ((unsigned)gy < (unsigned)HI));
        if (ok) {
            int idx = gy * WI + gx;
            xv = Xn[idx];
            yv = Yn[idx];
        }
        const float pxx = xv * xv, pyy = yv * yv, pxy = xv * yv;
#pragma unroll
        for (int r = 0; r < 4; ++r) {
            const int d = j - r;               // compile-time predicate
            if (d >= 0 && d < 7) {
                const float w = wv.w[d];
                acc[0][r] += w * xv;
                acc[1][r] += w * yv;
                acc[2][r] += w * pxx;
                acc[3][r] += w * pyy;
                acc[4][r] += w * pxy;
            }
        }
    }
    // 20 b32 writes; consecutive lanes -> consecutive ci -> conflict-free.
#pragma unroll
    for (int ch = 0; ch < 5; ++ch)
#pragma unroll
        for (int r = 0; r < 4; ++r)
            vbuf[ch * (TH * LSTR) + (band * 4 + r) * LSTR + ci] = acc[ch][r];
}

__global__ __launch_bounds__(320, 7) void ssim_kernel(
    const float* __restrict__ X, const float* __restrict__ Y,
    W7 wv, float* __restrict__ partial)
{
    __shared__ __align__(16) float vbuf[5 * TH * LSTR];   // 23040 B
    __shared__ float wsum[5];

    const int tid = threadIdx.x;
    const int tx0 = blockIdx.x * TW;
    const int ty0 = blockIdx.y * TH;
    const float* __restrict__ Xn = X + (size_t)blockIdx.z * (WI * HI);
    const float* __restrict__ Yn = Y + (size_t)blockIdx.z * (WI * HI);

    // ---- phase 1: vertical conv. 280 tasks = 4 bands x 70 cols, 1 per thread.
    // tid<256: band = tid>>6 (wave-uniform), ci = tid&63 (coalesced).
    // tid 256..279 (wave 4): the 24 halo-column tasks: band = e/6, ci = 64+e%6.
    const bool interior = (blockIdx.y >= 1) && (blockIdx.y <= GYD - 2);
    if (interior) {
        if (tid < 256) {
            column_task<true>(Xn, Yn, wv, vbuf, tx0, ty0, tid >> 6, tid & 63);
        } else if (tid < 280) {
            const int e = tid - 256;
            column_task<true>(Xn, Yn, wv, vbuf, tx0, ty0, e / 6, 64 + e % 6);
        }
    } else {
        if (tid < 256) {
            column_task<false>(Xn, Yn, wv, vbuf, tx0, ty0, tid >> 6, tid & 63);
        } else if (tid < 280) {
            const int e = tid - 256;
            column_task<false>(Xn, Yn, wv, vbuf, tx0, ty0, e / 6, 64 + e % 6);
        }
    }
    __syncthreads();

    // ---- phase 2: horizontal 7-tap + SSIM. 1024 px = 256 tasks of (row, 4 px).
    // vfilt LDS col c holds image tile col c-3; output x needs LDS cols x..x+6.
    // 16 consecutive lanes read 256 contiguous LDS bytes -> conflict-free.
    float lsum = 0.f;
    if (tid < 256) {
        const float C1 = 0.0004f, C2 = 0.0036f, COVN = 49.f / 48.f;
        const int row = tid >> 4;           // 0..15
        const int xg  = (tid & 15) << 2;    // 0,4,...,60

        float m[4][5];                      // 4 outputs x 5 channels
#pragma unroll
        for (int j = 0; j < 4; ++j)
#pragma unroll
            for (int ch = 0; ch < 5; ++ch) m[j][ch] = 0.f;

#pragma unroll
        for (int ch = 0; ch < 5; ++ch) {
            const v4* p = (const v4*)&vbuf[ch * (TH * LSTR) + row * LSTR + xg];
            v4 a = p[0], b = p[1], c = p[2];
            float f[12] = {a.x,a.y,a.z,a.w, b.x,b.y,b.z,b.w, c.x,c.y,c.z,c.w};
#pragma unroll
            for (int j = 0; j < 4; ++j) {
                float s = 0.f;
#pragma unroll
                for (int d = 0; d < 7; ++d) s += wv.w[d] * f[j + d];
                m[j][ch] = s;
            }
        }
#pragma unroll
        for (int j = 0; j < 4; ++j) {
            const float mx = m[j][0], my = m[j][1];
            const float mxsq = mx * mx;
            const float mysq = my * my;
            const float mxy  = mx * my;
            const float vx   = (m[j][2] - mxsq) * COVN;
            const float vy   = (m[j][3] - mysq) * COVN;
            const float vxy  = (m[j][4] - mxy)  * COVN;
            const float num  = (2.f * mxy + C1) * (2.f * vxy + C2);
            const float den  = (mxsq + mysq + C1) * (vx + vy + C2);
            lsum += num * __builtin_amdgcn_rcpf(den);
        }
    }

    // ---- block reduction -> per-block partial ----
#pragma unroll
    for (int off = 32; off > 0; off >>= 1)
        lsum += __shfl_down(lsum, off, 64);
    if ((tid & 63) == 0) wsum[tid >> 6] = lsum;
    __syncthreads();
    if (tid == 0) {
        int bid = (blockIdx.z * GYD + blockIdx.y) * GXD + blockIdx.x;
        partial[bid] = ((wsum[0] + wsum[1]) + (wsum[2] + wsum[3])) + wsum[4];
    }
}

__global__ __launch_bounds__(256) void ssim_finalize(
    const float* __restrict__ partial, float* __restrict__ out)
{
    __shared__ double ws[4];
    const int tid = threadIdx.x;
    double s = 0.0;
    for (int i = tid; i < NBLK; i += 256) s += (double)partial[i];
#pragma unroll
    for (int off = 32; off > 0; off >>= 1)
        s += __shfl_down(s, off, 64);
    if ((tid & 63) == 0) ws[tid >> 6] = s;
    __syncthreads();
    if (tid == 0)
        out[0] = (float)(1.0 - ((ws[0] + ws[1]) + (ws[2] + ws[3])) / NPIX);
}

extern "C" void kernel_launch(void* const* d_in, const int* in_sizes, int n_in,
                              void* d_out, int out_size, void* d_ws, size_t ws_size,
                              hipStream_t stream) {
    const float* X = (const float*)d_in[0];
    const float* Y = (const float*)d_in[1];
    // Exact 1D Gaussian weights in fp64 (7x7 window = outer product).
    W7 wv;
    {
        double g[7], s = 0.0;
        for (int i = 0; i < 7; ++i) {
            double x = (double)(i - 3);
            g[i] = exp(-(x * x) / (2.0 * 1.5 * 1.5));
            s += g[i];
        }
        for (int i = 0; i < 7; ++i) wv.w[i] = (float)(g[i] / s);
    }

    float* partial = (float*)d_ws;   // 6400 floats, fully written every launch

    dim3 grid(GXD, GYD, NI);
    ssim_kernel<<<grid, 320, 0, stream>>>(X, Y, wv, partial);
    ssim_finalize<<<1, 256, 0, stream>>>(partial, (float*)d_out);
}

// Round 5
// 114.322 us; speedup vs baseline: 1.1957x; 1.1957x over previous
//
#include <hip/hip_runtime.h>
#include <math.h>

// SSIM on MI355X, round 5: vertical-first separable conv, 64x16 tiles,
// 320 threads (280 column tasks 1:1), 23 KB LDS, NO min-occupancy
// launch_bounds (R4's ",7" caused 8 dwords/thread scratch spill -> 66 MB
// HBM writes). Phase 1 preloads all 20 row values before accumulating.

#define WI 320
#define HI 320
#define NI 64
#define TW 64
#define TH 16
#define GXD 5                  // WI/TW
#define GYD 20                 // HI/TH
#define NBLK (GXD * GYD * NI)  // 6400
#define LSTR 72                // vfilt row stride in floats (288 B, 16B-aligned)
#define NPIX ((double)NI * WI * HI)

typedef float v4 __attribute__((ext_vector_type(4)));

struct W7 { float w[7]; };

// Vertical 7-tap for one column task: band (4 output rows), vfilt column ci
// (0..69; image col = tx0+ci-3). Loads 10 rows x 2 images into registers,
// accumulates 5 channels x 4 rows, writes vfilt[ch][band*4+r][ci].
// YI: rows always in-bounds. XI: column always in-bounds.
template <bool YI, bool XI>
__device__ __forceinline__ void column_task(
    const float* __restrict__ Xn, const float* __restrict__ Yn,
    const W7& wv, float* __restrict__ vbuf, int tx0, int ty0, int band, int ci)
{
    const int gx   = tx0 + ci - 3;
    const bool xok = XI || ((unsigned)gx < (unsigned)WI);
    const int gy0  = ty0 + band * 4 - 3;

    // ---- preload: 20 coalesced loads issued back-to-back ----
    float xr[10], yr[10];
#pragma unroll
    for (int j = 0; j < 10; ++j) {
        const int gy  = gy0 + j;
        const bool ok = xok && (YI || ((unsigned)gy < (unsigned)HI));
        float xv = 0.f, yv = 0.f;
        if (ok) {
            const int idx = gy * WI + gx;
            xv = Xn[idx];
            yv = Yn[idx];
        }
        xr[j] = xv;
        yr[j] = yv;
    }

    // ---- accumulate 5 channels x 4 output rows ----
    float acc[5][4];
#pragma unroll
    for (int ch = 0; ch < 5; ++ch)
#pragma unroll
        for (int r = 0; r < 4; ++r) acc[ch][r] = 0.f;

#pragma unroll
    for (int j = 0; j < 10; ++j) {
        const float xv = xr[j], yv = yr[j];
        const float pxx = xv * xv, pyy = yv * yv, pxy = xv * yv;
#pragma unroll
        for (int r = 0; r < 4; ++r) {
            const int d = j - r;               // compile-time predicate
            if (d >= 0 && d < 7) {
                const float w = wv.w[d];
                acc[0][r] += w * xv;
                acc[1][r] += w * yv;
                acc[2][r] += w * pxx;
                acc[3][r] += w * pyy;
                acc[4][r] += w * pxy;
            }
        }
    }
    // 20 b32 writes; consecutive lanes -> consecutive ci -> conflict-free.
#pragma unroll
    for (int ch = 0; ch < 5; ++ch)
#pragma unroll
        for (int r = 0; r < 4; ++r)
            vbuf[ch * (TH * LSTR) + (band * 4 + r) * LSTR + ci] = acc[ch][r];
}

__global__ __launch_bounds__(320) void ssim_kernel(
    const float* __restrict__ X, const float* __restrict__ Y,
    W7 wv, float* __restrict__ partial)
{
    __shared__ __align__(16) float vbuf[5 * TH * LSTR];   // 23040 B
    __shared__ float wsum[5];

    const int tid = threadIdx.x;
    const int tx0 = blockIdx.x * TW;
    const int ty0 = blockIdx.y * TH;
    const float* __restrict__ Xn = X + (size_t)blockIdx.z * (WI * HI);
    const float* __restrict__ Yn = Y + (size_t)blockIdx.z * (WI * HI);

    // ---- phase 1: vertical conv. 280 tasks = 4 bands x 70 cols, 1 per thread.
    // tid<256: band = tid>>6 (wave-uniform), ci = tid&63 (coalesced).
    // tid 256..279 (wave 4): 24 halo-column tasks: band = e/6, ci = 64+e%6.
    const bool yi = (blockIdx.y >= 1) && (blockIdx.y <= GYD - 2);
    const bool xi = (blockIdx.x >= 1) && (blockIdx.x <= GXD - 2);
    if (tid < 280) {
        int band, ci;
        if (tid < 256) { band = tid >> 6; ci = tid & 63; }
        else           { const int e = tid - 256; band = e / 6; ci = 64 + e % 6; }
        if (yi) {
            if (xi) column_task<true, true >(Xn, Yn, wv, vbuf, tx0, ty0, band, ci);
            else    column_task<true, false>(Xn, Yn, wv, vbuf, tx0, ty0, band, ci);
        } else {
            if (xi) column_task<false, true >(Xn, Yn, wv, vbuf, tx0, ty0, band, ci);
            else    column_task<false, false>(Xn, Yn, wv, vbuf, tx0, ty0, band, ci);
        }
    }
    __syncthreads();

    // ---- phase 2: horizontal 7-tap + SSIM. 1024 px = 256 tasks of (row, 4 px).
    // vfilt LDS col c holds image tile col c-3; output x needs LDS cols x..x+6.
    // 16 consecutive lanes read 256 contiguous LDS bytes -> conflict-free.
    float lsum = 0.f;
    if (tid < 256) {
        const float C1 = 0.0004f, C2 = 0.0036f, COVN = 49.f / 48.f;
        const int row = tid >> 4;           // 0..15
        const int xg  = (tid & 15) << 2;    // 0,4,...,60

        float m[4][5];                      // 4 outputs x 5 channels
#pragma unroll
        for (int j = 0; j < 4; ++j)
#pragma unroll
            for (int ch = 0; ch < 5; ++ch) m[j][ch] = 0.f;

#pragma unroll
        for (int ch = 0; ch < 5; ++ch) {
            const v4* p = (const v4*)&vbuf[ch * (TH * LSTR) + row * LSTR + xg];
            v4 a = p[0], b = p[1], c = p[2];
            float f[12] = {a.x,a.y,a.z,a.w, b.x,b.y,b.z,b.w, c.x,c.y,c.z,c.w};
#pragma unroll
            for (int j = 0; j < 4; ++j) {
                float s = 0.f;
#pragma unroll
                for (int d = 0; d < 7; ++d) s += wv.w[d] * f[j + d];
                m[j][ch] = s;
            }
        }
#pragma unroll
        for (int j = 0; j < 4; ++j) {
            const float mx = m[j][0], my = m[j][1];
            const float mxsq = mx * mx;
            const float mysq = my * my;
            const float mxy  = mx * my;
            const float vx   = (m[j][2] - mxsq) * COVN;
            const float vy   = (m[j][3] - mysq) * COVN;
            const float vxy  = (m[j][4] - mxy)  * COVN;
            const float num  = (2.f * mxy + C1) * (2.f * vxy + C2);
            const float den  = (mxsq + mysq + C1) * (vx + vy + C2);
            lsum += num * __builtin_amdgcn_rcpf(den);
        }
    }

    // ---- block reduction -> per-block partial ----
#pragma unroll
    for (int off = 32; off > 0; off >>= 1)
        lsum += __shfl_down(lsum, off, 64);
    if ((tid & 63) == 0) wsum[tid >> 6] = lsum;
    __syncthreads();
    if (tid == 0) {
        int bid = (blockIdx.z * GYD + blockIdx.y) * GXD + blockIdx.x;
        partial[bid] = ((wsum[0] + wsum[1]) + (wsum[2] + wsum[3])) + wsum[4];
    }
}

__global__ __launch_bounds__(256) void ssim_finalize(
    const float* __restrict__ partial, float* __restrict__ out)
{
    __shared__ double ws[4];
    const int tid = threadIdx.x;
    double s = 0.0;
    for (int i = tid; i < NBLK; i += 256) s += (double)partial[i];
#pragma unroll
    for (int off = 32; off > 0; off >>= 1)
        s += __shfl_down(s, off, 64);
    if ((tid & 63) == 0) ws[tid >> 6] = s;
    __syncthreads();
    if (tid == 0)
        out[0] = (float)(1.0 - ((ws[0] + ws[1]) + (ws[2] + ws[3])) / NPIX);
}

extern "C" void kernel_launch(void* const* d_in, const int* in_sizes, int n_in,
                              void* d_out, int out_size, void* d_ws, size_t ws_size,
                              hipStream_t stream) {
    const float* X = (const float*)d_in[0];
    const float* Y = (const float*)d_in[1];
    // Exact 1D Gaussian weights in fp64 (7x7 window = outer product).
    W7 wv;
    {
        double g[7], s = 0.0;
        for (int i = 0; i < 7; ++i) {
            double x = (double)(i - 3);
            g[i] = exp(-(x * x) / (2.0 * 1.5 * 1.5));
            s += g[i];
        }
        for (int i = 0; i < 7; ++i) wv.w[i] = (float)(g[i] / s);
    }

    float* partial = (float*)d_ws;   // 6400 floats, fully written every launch

    dim3 grid(GXD, GYD, NI);
    ssim_kernel<<<grid, 320, 0, stream>>>(X, Y, wv, partial);
    ssim_finalize<<<1, 256, 0, stream>>>(partial, (float*)d_out);
}

// Round 6
// 110.792 us; speedup vs baseline: 1.2338x; 1.0319x over previous
//
#include <hip/hip_runtime.h>
#include <math.h>

// SSIM on MI355X, round 6: barrier-free wave-autonomous tiles.
// Each wave owns a 58x4 output strip: 64 lanes load the 64-col haloed window
// (coalesced), vertical 7-tap in registers, write its PRIVATE 5KB LDS region,
// wave-synchronous read-back for the horizontal 7-tap + SSIM. No __syncthreads
// between phases -> waves drift out of phase and VALU/LDS/VMEM pipes overlap.

#define WI 320
#define HI 320
#define NI 64
#define TWO 58                  // output cols per x-tile (64 loaded incl. halo)
#define GXD 6                   // ceil(320/58)
#define GYD 20                  // 16 output rows per block (4 waves x 4 rows)
#define NBLK (GXD * GYD * NI)   // 7680
#define NPIX ((double)NI * WI * HI)
#define WREG (5 * 4 * 64)       // per-wave LDS floats: 5 ch x 4 rows x 64 cols

typedef float v4 __attribute__((ext_vector_type(4)));

struct W7 { float w[7]; };

// One wave, one 58x4 strip. XM: 0 = left edge tile, 1 = interior, 2 = right.
// YI: all 10 input rows in-bounds. Returns this lane's SSIM partial sum.
template <bool YI, int XM>
__device__ __forceinline__ float wave_task(
    const float* __restrict__ Xn, const float* __restrict__ Yn,
    const W7& wv, float* __restrict__ vb, int x0, int y0, int lane)
{
    const int gx   = x0 + lane - 3;
    const bool xok = (XM == 1) || (XM == 0 ? (gx >= 0) : (gx < WI));

    // ---- 20 coalesced loads (lane = consecutive col), zero-pad OOB ----
    float xr[10], yr[10];
#pragma unroll
    for (int j = 0; j < 10; ++j) {
        const int gy  = y0 + j - 3;
        const bool ok = xok && (YI || ((unsigned)gy < (unsigned)HI));
        float xv = 0.f, yv = 0.f;
        if (ok) { const int idx = gy * WI + gx; xv = Xn[idx]; yv = Yn[idx]; }
        xr[j] = xv; yr[j] = yv;
    }

    // ---- vertical 7-tap, 5 channels x 4 output rows, in registers ----
    float acc[5][4];
#pragma unroll
    for (int ch = 0; ch < 5; ++ch)
#pragma unroll
        for (int r = 0; r < 4; ++r) acc[ch][r] = 0.f;
#pragma unroll
    for (int j = 0; j < 10; ++j) {
        const float xv = xr[j], yv = yr[j];
        const float pxx = xv * xv, pyy = yv * yv, pxy = xv * yv;
#pragma unroll
        for (int r = 0; r < 4; ++r) {
            const int d = j - r;                 // compile-time predicate
            if (d >= 0 && d < 7) {
                const float w = wv.w[d];
                acc[0][r] += w * xv;
                acc[1][r] += w * yv;
                acc[2][r] += w * pxx;
                acc[3][r] += w * pyy;
                acc[4][r] += w * pxy;
            }
        }
    }
    // 20 b32 writes to this wave's private region; col = lane (2-way = free).
#pragma unroll
    for (int ch = 0; ch < 5; ++ch)
#pragma unroll
        for (int r = 0; r < 4; ++r)
            vb[ch * 256 + r * 64 + lane] = acc[ch][r];

    __builtin_amdgcn_wave_barrier();   // scheduling fence; lgkmcnt orders the data

    // ---- horizontal 7-tap + SSIM. lane -> (row, 4 consecutive out cols) ----
    float lsum = 0.f;
    const int row = lane >> 4;
    const int xg  = (lane & 15) << 2;          // 0,4,...,60
    if (xg < TWO) {                            // xg==60 lanes idle
        const float C1 = 0.0004f, C2 = 0.0036f, COVN = 49.f / 48.f;
        float m[4][5];
#pragma unroll
        for (int j = 0; j < 4; ++j)
#pragma unroll
            for (int ch = 0; ch < 5; ++ch) m[j][ch] = 0.f;
#pragma unroll
        for (int ch = 0; ch < 5; ++ch) {
            const v4* p = (const v4*)&vb[ch * 256 + row * 64 + xg];
            v4 a = p[0], b = p[1], c = p[2];
            float f[12] = {a.x,a.y,a.z,a.w, b.x,b.y,b.z,b.w, c.x,c.y,c.z,c.w};
#pragma unroll
            for (int j = 0; j < 4; ++j) {
                float s = 0.f;
#pragma unroll
                for (int d = 0; d < 7; ++d) s += wv.w[d] * f[j + d];
                m[j][ch] = s;
            }
        }
#pragma unroll
        for (int j = 0; j < 4; ++j) {
            const float mx = m[j][0], my = m[j][1];
            const float mxsq = mx * mx;
            const float mysq = my * my;
            const float mxy  = mx * my;
            const float vx   = (m[j][2] - mxsq) * COVN;
            const float vy   = (m[j][3] - mysq) * COVN;
            const float vxy  = (m[j][4] - mxy)  * COVN;
            const float num  = (2.f * mxy + C1) * (2.f * vxy + C2);
            const float den  = (mxsq + mysq + C1) * (vx + vy + C2);
            const bool valid = (xg + j < TWO) && (XM != 2 || x0 + xg + j < WI);
            lsum += valid ? num * __builtin_amdgcn_rcpf(den) : 0.f;
        }
    }
    return lsum;
}

__global__ __launch_bounds__(256) void ssim_kernel(
    const float* __restrict__ X, const float* __restrict__ Y,
    W7 wv, float* __restrict__ partial)
{
    __shared__ __align__(16) float vbuf[4 * WREG + 16];  // +16 pad: b128 tail overrun
    __shared__ float wsum[4];

    const int tid  = threadIdx.x;
    const int lane = tid & 63;
    const int w    = tid >> 6;
    const int x0   = blockIdx.x * TWO;
    const int y0   = blockIdx.y * 16 + w * 4;  // first output row of this wave
    const float* __restrict__ Xn = X + (size_t)blockIdx.z * (WI * HI);
    const float* __restrict__ Yn = Y + (size_t)blockIdx.z * (WI * HI);
    float* vb = vbuf + w * WREG;

    const bool yi = (y0 >= 3) && (y0 <= HI - 7);  // all 10 input rows in-bounds
    const int  xm = (blockIdx.x == 0) ? 0 : ((blockIdx.x == GXD - 1) ? 2 : 1);

    float lsum;
    if (yi) {
        if      (xm == 0) lsum = wave_task<true, 0>(Xn, Yn, wv, vb, x0, y0, lane);
        else if (xm == 1) lsum = wave_task<true, 1>(Xn, Yn, wv, vb, x0, y0, lane);
        else              lsum = wave_task<true, 2>(Xn, Yn, wv, vb, x0, y0, lane);
    } else {
        if      (xm == 0) lsum = wave_task<false, 0>(Xn, Yn, wv, vb, x0, y0, lane);
        else if (xm == 1) lsum = wave_task<false, 1>(Xn, Yn, wv, vb, x0, y0, lane);
        else              lsum = wave_task<false, 2>(Xn, Yn, wv, vb, x0, y0, lane);
    }

    // ---- reduction: wave shuffle -> LDS -> single barrier -> block partial ----
#pragma unroll
    for (int off = 32; off > 0; off >>= 1)
        lsum += __shfl_down(lsum, off, 64);
    if (lane == 0) wsum[w] = lsum;
    __syncthreads();
    if (tid == 0) {
        const int bid = (blockIdx.z * GYD + blockIdx.y) * GXD + blockIdx.x;
        partial[bid] = (wsum[0] + wsum[1]) + (wsum[2] + wsum[3]);
    }
}

__global__ __launch_bounds__(256) void ssim_finalize(
    const float* __restrict__ partial, float* __restrict__ out)
{
    __shared__ double ws[4];
    const int tid = threadIdx.x;
    double s = 0.0;
    for (int i = tid; i < NBLK; i += 256) s += (double)partial[i];
#pragma unroll
    for (int off = 32; off > 0; off >>= 1)
        s += __shfl_down(s, off, 64);
    if ((tid & 63) == 0) ws[tid >> 6] = s;
    __syncthreads();
    if (tid == 0)
        out[0] = (float)(1.0 - ((ws[0] + ws[1]) + (ws[2] + ws[3])) / NPIX);
}

extern "C" void kernel_launch(void* const* d_in, const int* in_sizes, int n_in,
                              void* d_out, int out_size, void* d_ws, size_t ws_size,
                              hipStream_t stream) {
    const float* X = (const float*)d_in[0];
    const float* Y = (const float*)d_in[1];
    // Exact 1D Gaussian weights in fp64 (7x7 window = outer product).
    W7 wv;
    {
        double g[7], s = 0.0;
        for (int i = 0; i < 7; ++i) {
            double x = (double)(i - 3);
            g[i] = exp(-(x * x) / (2.0 * 1.5 * 1.5));
            s += g[i];
        }
        for (int i = 0; i < 7; ++i) wv.w[i] = (float)(g[i] / s);
    }

    float* partial = (float*)d_ws;   // 7680 floats, fully written every launch

    dim3 grid(GXD, GYD, NI);
    ssim_kernel<<<grid, 256, 0, stream>>>(X, Y, wv, partial);
    ssim_finalize<<<1, 256, 0, stream>>>(partial, (float*)d_out);
}